// Round 19
// baseline (141.729 us; speedup 1.0000x reference)
//
#include <hip/hip_runtime.h>
#include <hip/hip_bf16.h>
#include <math.h>

#define BATCH 4096
#define FEAT 128
#define C_TOTAL 16384
#define OUT_TYPES 512

typedef short bf16x8 __attribute__((ext_vector_type(8)));
typedef float f32x4 __attribute__((ext_vector_type(4)));
typedef unsigned short u16;

typedef const __attribute__((address_space(1))) void cg_void;
typedef __attribute__((address_space(3))) void lds_void_t;

static __device__ __forceinline__ u16 f2bf(float f) {
    __hip_bfloat16 h = __float2bfloat16(f);
    return reinterpret_cast<u16&>(h);
}

// ---------------- prologue: out=bias bcast | centres prep | x prep -----------
__global__ void prologue_kernel(const float* __restrict__ x, const float* __restrict__ centres,
                                const float* __restrict__ ls, const float* __restrict__ bias,
                                u16* __restrict__ xb, u16* __restrict__ cbb,
                                float* __restrict__ cc, float* __restrict__ scale,
                                float* __restrict__ hc, float* __restrict__ xx,
                                float* __restrict__ out) {
    const int b = blockIdx.x;
    const int t = threadIdx.x;
    if (b < 2048) {                       // out[m][n] = bias[n], 8 MB
        int i = b * 256 + t;              // float4 index
        float4 bv = reinterpret_cast<const float4*>(bias)[i & 127];
        reinterpret_cast<float4*>(out)[i] = bv;
        return;
    }
    const bool is_c = (b < 2048 + 256);
    const int row = (is_c ? (b - 2048) : (b - 2304)) * 64 + (t >> 2);
    const int l4 = t & 3;
    const float* src = is_c ? centres : x;
    u16* dstb = is_c ? cbb : xb;
    const float4* p = reinterpret_cast<const float4*>(src + (size_t)row * FEAT);
    ushort4* q = reinterpret_cast<ushort4*>(dstb + (size_t)row * FEAT);
    float s = 0.f;
#pragma unroll
    for (int i = 0; i < 8; ++i) {
        float4 v = p[i * 4 + l4];
        s += v.x * v.x + v.y * v.y + v.z * v.z + v.w * v.w;
        ushort4 h;
        h.x = f2bf(v.x); h.y = f2bf(v.y); h.z = f2bf(v.z); h.w = f2bf(v.w);
        q[i * 4 + l4] = h;
    }
    s += __shfl_xor(s, 1);
    s += __shfl_xor(s, 2);
    if (l4 == 0) {
        if (is_c) {
            cc[row] = s;
            scale[row] = __expf(2.f * ls[row]);
            // exact fire condition: sqd*scale < 96 <=> d - 0.5*xx > 0.5*cc - 48/scale
            hc[row] = 0.5f * s - 48.f * __expf(-2.f * ls[row]);
        } else {
            xx[row] = s;
        }
    }
}

// ---------------- rbf: wave-autonomous MFMA, 3 blocks/CU ---------------------
// r12/r18 wave program UNCHANGED (128x16 wave-tile, af[8][4], 32 MFMA/iter,
// 2-iter staged lead, counted vmcnt 8/4/0, tight screen, zero barriers).
// Single variable vs r18: waves/SIMD. 3 LDS bufs/wave (12 KB) -> 48 KB/block
// -> 3 blocks/CU; CSPLIT=32 (NIT=8) -> grid 1024 so the third block slot
// actually fills (r5/r10 asked for co-residency the grid couldn't deliver).
// Buffer reuse safety: buf (it+2)%3 was last ds_read at iter it-1 — those
// reads retired (data consumed by MFMAs) before this iter's STAGE issues,
// and the load's LDS write lands strictly after issue. Same-wave order.
#define BM 128
#define BNW 16                    /* centres per wave-iter */
#define NIT 8                     /* iters -> 128 centres per wave */
#define CSPLIT 32                 /* 32 chunks of 512 centres (4 waves) */

__global__ __launch_bounds__(256, 3)
void rbf_kernel(const u16* __restrict__ xb, const u16* __restrict__ cb,
                const float* __restrict__ hc, const float* __restrict__ cc,
                const float* __restrict__ scale, const int* __restrict__ node_id,
                const float* __restrict__ xx, const float* __restrict__ W,
                float* __restrict__ out) {
    __shared__ u16 cs[4][3][BNW * FEAT];  // [wave][buf][4 KB] = 48 KB

    const int t = threadIdx.x;
    const int lane = t & 63;
    const int w = t >> 6;                 // wave 0..3 (independent)
    const int q = lane >> 4;              // 0..3
    const int r = lane & 15;
    // bijective XCD remap: 1024 = 8 XCD x 128; XCD k: 32 rowblocks x 4 chunks
    const int bid = blockIdx.x;
    const int nid = (bid & 7) * 128 + (bid >> 3);
    const int row0 = (nid & 31) * BM;
    const int cw0 = (nid >> 5) * 512 + w * (BNW * NIT);  // wave's 128 centres
    const int swz = r & 7;

    // ---- setup: all global metadata consumed before staging ----
    bf16x8 af[8][4];
#pragma unroll
    for (int m = 0; m < 8; ++m) {
        const u16* xrow = xb + (size_t)(row0 + m * 16 + r) * FEAT + q * 8;
#pragma unroll
        for (int ks = 0; ks < 4; ++ks)
            af[m][ks] = *reinterpret_cast<const bf16x8*>(xrow + ks * 32);
    }
    // per-m acc bias: -0.5 * min(xx) over the 4 rows this lane owns in group m
    float nx4[8];
#pragma unroll
    for (int m = 0; m < 8; ++m) {
        float4 v = *reinterpret_cast<const float4*>(&xx[row0 + m * 16 + q * 4]);
        nx4[m] = -0.5f * fminf(fminf(v.x, v.y), fminf(v.z, v.w));
    }
    // per-iter per-lane threshold (exact hc of this lane's centre)
    float hv[NIT];
#pragma unroll
    for (int it = 0; it < NIT; ++it)
        hv[it] = hc[cw0 + it * BNW + r];

    // ---- per-wave staging: 4 KB tile, 4 loads (linear dest, swz source) ----
#define STAGE(IT, BUF)                                                         \
    {                                                                          \
        _Pragma("unroll")                                                      \
        for (int p = 0; p < 4; ++p) {                                          \
            int G = lane + p * 64;                                             \
            int rr = G >> 4;                                                   \
            int gsrc = (G & 15) ^ (rr & 7);                                    \
            __builtin_amdgcn_global_load_lds(                                  \
                (cg_void*)(cb + (size_t)(cw0 + (IT) * BNW + rr) * FEAT + gsrc * 8), \
                (lds_void_t*)((char*)cs[w][BUF] + G * 16), 16, 0, 0);          \
        }                                                                      \
    }
    STAGE(0, 0)
    STAGE(1, 1)

    unsigned sus = 0;
#pragma unroll
    for (int it = 0; it < NIT; ++it) {
        if (it + 2 < NIT) STAGE(it + 2, (it + 2) % 3)  // buf last read at it-1 (same wave)
        // wait own tile-it loads only (tiles it+1, it+2 stay in flight)
        if (it + 2 < NIT)      asm volatile("s_waitcnt vmcnt(8)" ::: "memory");
        else if (it + 1 < NIT) asm volatile("s_waitcnt vmcnt(4)" ::: "memory");
        else                   asm volatile("s_waitcnt vmcnt(0)" ::: "memory");
        __builtin_amdgcn_sched_barrier(0);

        const u16* brow = cs[w][it % 3] + r * FEAT;
        f32x4 acc[8];
#pragma unroll
        for (int m = 0; m < 8; ++m)
            acc[m] = f32x4{nx4[m], nx4[m], nx4[m], nx4[m]};
        __builtin_amdgcn_s_setprio(1);
#pragma unroll
        for (int ks = 0; ks < 4; ++ks) {
            int gk = (ks * 4 + q) ^ swz;
            bf16x8 bf = *reinterpret_cast<const bf16x8*>(brow + gk * 8);
#pragma unroll
            for (int m = 0; m < 8; ++m)
                acc[m] = __builtin_amdgcn_mfma_f32_16x16x32_bf16(af[m][ks], bf, acc[m], 0, 0, 0);
        }
        __builtin_amdgcn_s_setprio(0);

        // tight screen: per-m max vs per-iter exact threshold
        const float hvi = hv[it];
        int fire = 0;
#pragma unroll
        for (int m = 0; m < 8; ++m) {
            float pm = fmaxf(fmaxf(acc[m][0], acc[m][1]), fmaxf(acc[m][2], acc[m][3]));
            fire |= (pm > hvi) ? 1 : 0;
        }
        sus |= ((unsigned)fire) << it;
    }
#undef STAGE

    // ---- cold exact path (never taken on this data; correct if taken) ----
    if (__builtin_expect(__any((int)(sus != 0u)), 0)) {
        for (int it = 0; it < NIT; ++it) {
            if (!__any((int)(sus & (1u << it)))) continue;
            const u16* p = cb + (size_t)(cw0 + it * BNW + r) * FEAT + q * 8;
            bf16x8 cf[4];
#pragma unroll
            for (int ks = 0; ks < 4; ++ks)
                cf[ks] = *reinterpret_cast<const bf16x8*>(p + ks * 32);
            f32x4 acc[8];
#pragma unroll
            for (int m = 0; m < 8; ++m) acc[m] = f32x4{0.f, 0.f, 0.f, 0.f};
#pragma unroll
            for (int ks = 0; ks < 4; ++ks)
#pragma unroll
                for (int m = 0; m < 8; ++m)
                    acc[m] = __builtin_amdgcn_mfma_f32_16x16x32_bf16(af[m][ks], cf[ks], acc[m], 0, 0, 0);
            const int c = cw0 + it * BNW + r;
            const float ccv = cc[c], sv = scale[c];
            const int nd = node_id[c];
#pragma unroll
            for (int m = 0; m < 8; ++m) {
#pragma unroll
                for (int j = 0; j < 4; ++j) {
                    const int row = row0 + m * 16 + q * 4 + j;
                    float sqd = fmaxf(xx[row] + ccv - 2.f * acc[m][j], 0.f);
                    float tt = sqd * sv;
                    if (tt < 96.f) {
                        float phi = __expf(-tt);
                        float* orow = out + (size_t)row * OUT_TYPES;
                        const float* wcp = W + nd;
                        for (int n = 0; n < OUT_TYPES; ++n)
                            atomicAdd(&orow[n], phi * wcp[(size_t)n * OUT_TYPES]);
                    }
                }
            }
        }
    }
}

// ---------------- launch ------------------------------------------------------
extern "C" void kernel_launch(void* const* d_in, const int* in_sizes, int n_in,
                              void* d_out, int out_size, void* d_ws, size_t ws_size,
                              hipStream_t stream) {
    const float* x       = (const float*)d_in[0];
    const float* centres = (const float*)d_in[1];
    const float* ls      = (const float*)d_in[2];
    const int*   node_id = (const int*)d_in[3];
    const float* W       = (const float*)d_in[4];
    const float* bias    = (const float*)d_in[5];
    float* out = (float*)d_out;

    // ws: xb 1MB | cbb 4MB | cc 64KB | scale 64KB | hc 64KB | xx 16KB
    char* p = (char*)d_ws;
    u16*   xb    = (u16*)p;    p += (size_t)BATCH * FEAT * 2;
    u16*   cbb   = (u16*)p;    p += (size_t)C_TOTAL * FEAT * 2;
    float* cc    = (float*)p;  p += (size_t)C_TOTAL * 4;
    float* scale = (float*)p;  p += (size_t)C_TOTAL * 4;
    float* hc    = (float*)p;  p += (size_t)C_TOTAL * 4;
    float* xx    = (float*)p;  p += (size_t)BATCH * 4;

    hipLaunchKernelGGL(prologue_kernel, dim3(2048 + 256 + 64), dim3(256), 0, stream,
                       x, centres, ls, bias, xb, cbb, cc, scale, hc, xx, out);
    hipLaunchKernelGGL(rbf_kernel, dim3((BATCH / BM) * CSPLIT), dim3(256), 0, stream,
                       xb, cbb, hc, cc, scale, node_id, xx, W, out);
}

// Round 20
// 30.533 us; speedup vs baseline: 4.6419x; 4.6419x over previous
//
#include <hip/hip_runtime.h>
#include <hip/hip_bf16.h>
#include <math.h>

#define BATCH 4096
#define FEAT 128
#define C_TOTAL 16384
#define OUT_TYPES 512

typedef short bf16x8 __attribute__((ext_vector_type(8)));
typedef float f32x4 __attribute__((ext_vector_type(4)));
typedef unsigned short u16;

typedef const __attribute__((address_space(1))) void cg_void;
typedef __attribute__((address_space(3))) void lds_void_t;

static __device__ __forceinline__ u16 f2bf(float f) {
    __hip_bfloat16 h = __float2bfloat16(f);
    return reinterpret_cast<u16&>(h);
}

// ---------------- prologue: out=bias bcast | centres prep | x prep -----------
__global__ void prologue_kernel(const float* __restrict__ x, const float* __restrict__ centres,
                                const float* __restrict__ ls, const float* __restrict__ bias,
                                u16* __restrict__ xb, u16* __restrict__ cbb,
                                float* __restrict__ cc, float* __restrict__ scale,
                                float* __restrict__ hc, float* __restrict__ xx,
                                float* __restrict__ out) {
    const int b = blockIdx.x;
    const int t = threadIdx.x;
    if (b < 2048) {                       // out[m][n] = bias[n], 8 MB
        int i = b * 256 + t;              // float4 index
        float4 bv = reinterpret_cast<const float4*>(bias)[i & 127];
        reinterpret_cast<float4*>(out)[i] = bv;
        return;
    }
    const bool is_c = (b < 2048 + 256);
    const int row = (is_c ? (b - 2048) : (b - 2304)) * 64 + (t >> 2);
    const int l4 = t & 3;
    const float* src = is_c ? centres : x;
    u16* dstb = is_c ? cbb : xb;
    const float4* p = reinterpret_cast<const float4*>(src + (size_t)row * FEAT);
    ushort4* q = reinterpret_cast<ushort4*>(dstb + (size_t)row * FEAT);
    float s = 0.f;
#pragma unroll
    for (int i = 0; i < 8; ++i) {
        float4 v = p[i * 4 + l4];
        s += v.x * v.x + v.y * v.y + v.z * v.z + v.w * v.w;
        ushort4 h;
        h.x = f2bf(v.x); h.y = f2bf(v.y); h.z = f2bf(v.z); h.w = f2bf(v.w);
        q[i * 4 + l4] = h;
    }
    s += __shfl_xor(s, 1);
    s += __shfl_xor(s, 2);
    if (l4 == 0) {
        if (is_c) {
            cc[row] = s;
            scale[row] = __expf(2.f * ls[row]);
            // exact fire condition: sqd*scale < 96 <=> d - 0.5*xx > 0.5*cc - 48/scale
            hc[row] = 0.5f * s - 48.f * __expf(-2.f * ls[row]);
        } else {
            xx[row] = s;
        }
    }
}

// ---------------- rbf: wave-autonomous MFMA, ZERO barriers (final) -----------
// 256 thr / 4 INDEPENDENT waves; wave w only ever consumes B-rows w*16..+15,
// so it stages its own 16-centre tile (4 KB) into its private LDS quarter via
// global_load_lds w=16 (pre-swizzled source), 4-buffer rotation, STAGE(it+2)
// before counted s_waitcnt vmcnt(8) -> 2-iter lead. Buffer reuse is same-wave
// program-ordered => race-free with NO s_barrier in the entire kernel.
// Wave-tile 128 rows x 16 cols: af[8][4]=128 VGPR, 32 MFMA/iter. NOTE: this
// wave program requires 128 VGPRs resident; launch_bounds(256,2) is the max
// occupancy that avoids scratch (r7/r15/r19 all spilled chasing more waves).
// Tight screen: acc init = per-m -0.5*min(xx of 4 rows); vs per-iter
// per-lane hv[it]=hc[c] (~6.9 sigma). Cold exact path post-loop via bitmask.
#define BM 128
#define BNW 16                    /* centres per wave-iter */
#define NIT 16                    /* iters -> 256 centres per wave */
#define CSPLIT 16                 /* 16 chunks of 1024 centres (4 waves) */

__global__ __launch_bounds__(256, 2)
void rbf_kernel(const u16* __restrict__ xb, const u16* __restrict__ cb,
                const float* __restrict__ hc, const float* __restrict__ cc,
                const float* __restrict__ scale, const int* __restrict__ node_id,
                const float* __restrict__ xx, const float* __restrict__ W,
                float* __restrict__ out) {
    __shared__ u16 cs[4][4][BNW * FEAT];  // [wave][buf][4 KB]

    const int t = threadIdx.x;
    const int lane = t & 63;
    const int w = t >> 6;                 // wave 0..3 (independent)
    const int q = lane >> 4;              // 0..3
    const int r = lane & 15;
    // bijective XCD remap: 512 blocks = 8 XCD x 64 (32 row-blocks x 2 chunks)
    const int bid = blockIdx.x;
    const int nid = (bid & 7) * 64 + (bid >> 3);
    const int row0 = (nid & 31) * BM;
    const int cw0 = (nid >> 5) * 1024 + w * (BNW * NIT);  // wave's 256 centres
    const int swz = r & 7;

    // ---- setup: all global metadata consumed before staging ----
    bf16x8 af[8][4];
#pragma unroll
    for (int m = 0; m < 8; ++m) {
        const u16* xrow = xb + (size_t)(row0 + m * 16 + r) * FEAT + q * 8;
#pragma unroll
        for (int ks = 0; ks < 4; ++ks)
            af[m][ks] = *reinterpret_cast<const bf16x8*>(xrow + ks * 32);
    }
    // per-m acc bias: -0.5 * min(xx) over the 4 rows this lane owns in group m
    float nx4[8];
#pragma unroll
    for (int m = 0; m < 8; ++m) {
        float4 v = *reinterpret_cast<const float4*>(&xx[row0 + m * 16 + q * 4]);
        nx4[m] = -0.5f * fminf(fminf(v.x, v.y), fminf(v.z, v.w));
    }
    // per-iter per-lane threshold (exact hc of this lane's centre)
    float hv[NIT];
#pragma unroll
    for (int it = 0; it < NIT; ++it)
        hv[it] = hc[cw0 + it * BNW + r];

    // ---- per-wave staging: 4 KB tile, 4 loads (linear dest, swz source) ----
#define STAGE(IT, BUF)                                                         \
    {                                                                          \
        _Pragma("unroll")                                                      \
        for (int p = 0; p < 4; ++p) {                                          \
            int G = lane + p * 64;                                             \
            int rr = G >> 4;                                                   \
            int gsrc = (G & 15) ^ (rr & 7);                                    \
            __builtin_amdgcn_global_load_lds(                                  \
                (cg_void*)(cb + (size_t)(cw0 + (IT) * BNW + rr) * FEAT + gsrc * 8), \
                (lds_void_t*)((char*)cs[w][BUF] + G * 16), 16, 0, 0);          \
        }                                                                      \
    }
    STAGE(0, 0)
    STAGE(1, 1)

    unsigned sus = 0;
#pragma unroll
    for (int it = 0; it < NIT; ++it) {
        if (it + 2 < NIT) STAGE(it + 2, (it + 2) & 3)  // buf last read at it-2 (same wave)
        // wait own tile-it loads only (tiles it+1, it+2 stay in flight)
        if (it + 2 < NIT)      asm volatile("s_waitcnt vmcnt(8)" ::: "memory");
        else if (it + 1 < NIT) asm volatile("s_waitcnt vmcnt(4)" ::: "memory");
        else                   asm volatile("s_waitcnt vmcnt(0)" ::: "memory");
        __builtin_amdgcn_sched_barrier(0);

        const u16* brow = cs[w][it & 3] + r * FEAT;
        f32x4 acc[8];
#pragma unroll
        for (int m = 0; m < 8; ++m)
            acc[m] = f32x4{nx4[m], nx4[m], nx4[m], nx4[m]};
        __builtin_amdgcn_s_setprio(1);
#pragma unroll
        for (int ks = 0; ks < 4; ++ks) {
            int gk = (ks * 4 + q) ^ swz;
            bf16x8 bf = *reinterpret_cast<const bf16x8*>(brow + gk * 8);
#pragma unroll
            for (int m = 0; m < 8; ++m)
                acc[m] = __builtin_amdgcn_mfma_f32_16x16x32_bf16(af[m][ks], bf, acc[m], 0, 0, 0);
        }
        __builtin_amdgcn_s_setprio(0);

        // tight screen: per-m max vs per-iter exact threshold
        const float hvi = hv[it];
        int fire = 0;
#pragma unroll
        for (int m = 0; m < 8; ++m) {
            float pm = fmaxf(fmaxf(acc[m][0], acc[m][1]), fmaxf(acc[m][2], acc[m][3]));
            fire |= (pm > hvi) ? 1 : 0;
        }
        sus |= ((unsigned)fire) << it;
    }
#undef STAGE

    // ---- cold exact path (never taken on this data; correct if taken) ----
    if (__builtin_expect(__any((int)(sus != 0u)), 0)) {
        for (int it = 0; it < NIT; ++it) {
            if (!__any((int)(sus & (1u << it)))) continue;
            const u16* p = cb + (size_t)(cw0 + it * BNW + r) * FEAT + q * 8;
            bf16x8 cf[4];
#pragma unroll
            for (int ks = 0; ks < 4; ++ks)
                cf[ks] = *reinterpret_cast<const bf16x8*>(p + ks * 32);
            f32x4 acc[8];
#pragma unroll
            for (int m = 0; m < 8; ++m) acc[m] = f32x4{0.f, 0.f, 0.f, 0.f};
#pragma unroll
            for (int ks = 0; ks < 4; ++ks)
#pragma unroll
                for (int m = 0; m < 8; ++m)
                    acc[m] = __builtin_amdgcn_mfma_f32_16x16x32_bf16(af[m][ks], cf[ks], acc[m], 0, 0, 0);
            const int c = cw0 + it * BNW + r;
            const float ccv = cc[c], sv = scale[c];
            const int nd = node_id[c];
#pragma unroll
            for (int m = 0; m < 8; ++m) {
#pragma unroll
                for (int j = 0; j < 4; ++j) {
                    const int row = row0 + m * 16 + q * 4 + j;
                    float sqd = fmaxf(xx[row] + ccv - 2.f * acc[m][j], 0.f);
                    float tt = sqd * sv;
                    if (tt < 96.f) {
                        float phi = __expf(-tt);
                        float* orow = out + (size_t)row * OUT_TYPES;
                        const float* wcp = W + nd;
                        for (int n = 0; n < OUT_TYPES; ++n)
                            atomicAdd(&orow[n], phi * wcp[(size_t)n * OUT_TYPES]);
                    }
                }
            }
        }
    }
}

// ---------------- launch ------------------------------------------------------
extern "C" void kernel_launch(void* const* d_in, const int* in_sizes, int n_in,
                              void* d_out, int out_size, void* d_ws, size_t ws_size,
                              hipStream_t stream) {
    const float* x       = (const float*)d_in[0];
    const float* centres = (const float*)d_in[1];
    const float* ls      = (const float*)d_in[2];
    const int*   node_id = (const int*)d_in[3];
    const float* W       = (const float*)d_in[4];
    const float* bias    = (const float*)d_in[5];
    float* out = (float*)d_out;

    // ws: xb 1MB | cbb 4MB | cc 64KB | scale 64KB | hc 64KB | xx 16KB
    char* p = (char*)d_ws;
    u16*   xb    = (u16*)p;    p += (size_t)BATCH * FEAT * 2;
    u16*   cbb   = (u16*)p;    p += (size_t)C_TOTAL * FEAT * 2;
    float* cc    = (float*)p;  p += (size_t)C_TOTAL * 4;
    float* scale = (float*)p;  p += (size_t)C_TOTAL * 4;
    float* hc    = (float*)p;  p += (size_t)C_TOTAL * 4;
    float* xx    = (float*)p;  p += (size_t)BATCH * 4;

    hipLaunchKernelGGL(prologue_kernel, dim3(2048 + 256 + 64), dim3(256), 0, stream,
                       x, centres, ls, bias, xb, cbb, cc, scale, hc, xx, out);
    hipLaunchKernelGGL(rbf_kernel, dim3((BATCH / BM) * CSPLIT), dim3(256), 0, stream,
                       xb, cbb, hc, cc, scale, node_id, xx, W, out);
}